// Round 13
// baseline (796.420 us; speedup 1.0000x reference)
//
#include <hip/hip_runtime.h>
#include <hip/hip_fp16.h>
#include <math.h>

#define BSTRIDE 5000   // bucket capacity: Poisson(4092), +14 sigma safety

typedef _Float16 half8 __attribute__((ext_vector_type(8)));
typedef float    f32x4 __attribute__((ext_vector_type(4)));

// ---------- helpers ----------
__device__ __forceinline__ float elu_f(float v) {
    return v > 0.f ? v : expm1f(v);
}
__device__ __forceinline__ unsigned pack2h(float a, float b) {
    __half2 h = __floats2half2_rn(a, b);
    return *(unsigned*)&h;
}
__device__ __forceinline__ float2 unpack2h(unsigned u) {
    __half2 h = *(__half2*)&u;
    return __half22float2(h);
}
// granule swizzle within a 64-fp16 row: spreads the 16B granules across banks
__device__ __forceinline__ int swz(int line, int e) {
    return ((((e >> 3) ^ (line & 7)) << 3) | (e & 7));
}

// ---------- kA: partition edges into dst-buckets (dst>>8); 391 hot cursors ----------
__global__ __launch_bounds__(256) void k_part(const int* __restrict__ src,
                                              const int* __restrict__ dst,
                                              const float* __restrict__ ew,
                                              unsigned* __restrict__ gcur,
                                              uint2* __restrict__ scratch, int E) {
    int i = blockIdx.x * 256 + threadIdx.x;
    if (i >= E) return;
    int s = src[i], d = dst[i];
    unsigned ewq = (unsigned)(ew[i] * 32768.0f);
    if (ewq > 32767u) ewq = 32767u;
    unsigned se = ((unsigned)s << 15) | ewq;        // s:17b | ew:15b fixed point
    int b = d >> 8;
    unsigned pos = atomicAdd(&gcur[b], 1u);
    scratch[(size_t)b * BSTRIDE + pos] = make_uint2(se, (unsigned)(d & 255));
}

// ---------- kB: exclusive scan of 391 bucket sizes -> bbase ; rowptr[N] = E ----------
__global__ __launch_bounds__(512) void k_bscan(const unsigned* __restrict__ gcur,
                                               unsigned* __restrict__ bbase,
                                               int nb, int* __restrict__ rowptr,
                                               int n, int E) {
    __shared__ unsigned sm[512];
    int t = threadIdx.x;
    unsigned v = (t < nb) ? gcur[t] : 0u;
    sm[t] = v;
    __syncthreads();
    for (int off = 1; off < 512; off <<= 1) {
        unsigned x = sm[t];
        unsigned y = (t >= off) ? sm[t - off] : 0u;
        __syncthreads();
        sm[t] = x + y;
        __syncthreads();
    }
    if (t < nb) bbase[t] = sm[t] - v;   // exclusive
    if (t == 0) rowptr[n] = E;
}

// ---------- kC: per-bucket CSR build, LDS atomics only ----------
// Writes rowptr, dinv for its <=256 nodes; meta (u32 = s|ewq) into contiguous region.
__global__ __launch_bounds__(256) void k_bucket(const uint2* __restrict__ scratch,
                                                const unsigned* __restrict__ gcur,
                                                const unsigned* __restrict__ bbase,
                                                int* __restrict__ rowptr,
                                                float* __restrict__ dinv,
                                                unsigned* __restrict__ meta,
                                                int n) {
    __shared__ unsigned scnt[256];
    __shared__ float    sdeg[256];
    __shared__ unsigned srp[256];
    __shared__ unsigned char rankbuf[BSTRIDE];
    int b = blockIdx.x;
    int t = threadIdx.x;
    int nodes = n - b * 256; if (nodes > 256) nodes = 256;
    int ecnt = (int)gcur[b];
    unsigned base = bbase[b];
    scnt[t] = 0u;
    sdeg[t] = 0.f;
    __syncthreads();
    const uint2* sc = scratch + (size_t)b * BSTRIDE;
    // sweep 1: per-node count + weighted degree; remember each edge's rank
    for (int i = t; i < ecnt; i += 256) {
        uint2 r = sc[i];
        unsigned dl = r.y;
        unsigned rank = atomicAdd(&scnt[dl], 1u);
        rankbuf[i] = (unsigned char)rank;               // max degree << 256
        float ewv = (float)(r.x & 32767u) * (1.0f / 32768.0f);
        atomicAdd(&sdeg[dl], ewv);
    }
    __syncthreads();
    // exclusive scan of scnt -> srp
    unsigned v = scnt[t];
    srp[t] = v;
    __syncthreads();
    for (int off = 1; off < 256; off <<= 1) {
        unsigned x = srp[t];
        unsigned y = (t >= off) ? srp[t - off] : 0u;
        __syncthreads();
        srp[t] = x + y;
        __syncthreads();
    }
    unsigned excl = srp[t] - v;
    srp[t] = excl;                 // each thread rewrites only its own slot
    if (t < nodes) {
        int g = b * 256 + t;
        rowptr[g] = (int)(base + excl);
        dinv[g]   = rsqrtf(sdeg[t] + 1.0f);
    }
    __syncthreads();
    // sweep 2: place edges
    for (int i = t; i < ecnt; i += 256) {
        uint2 r = sc[i];
        unsigned pos = srp[r.y] + (unsigned)rankbuf[i];
        meta[base + pos] = r.x;
    }
}

// ---------- K-front (MFMA): y1 = dinv*(X@W1) ; xf = elu(X@Wf+bf) ; y2 = dinv*(xf@W2) ----------
// Block = 64 node rows, 4 waves. Output: xw12[node*64+col] = packed fp16 (y1, y2).
__global__ __launch_bounds__(256) void k_front(
    const int* __restrict__ node_index,
    const float* __restrict__ emb,
    const float* __restrict__ W1,
    const float* __restrict__ Wf,
    const float* __restrict__ bfv,
    const float* __restrict__ W2,
    const float* __restrict__ dinv,
    unsigned* __restrict__ xw12,
    int n)
{
    __shared__ _Float16 sX[64 * 64];       // 8 KB, later overwritten by xf (own rows only)
    __shared__ _Float16 sWt[3 * 64 * 64];  // 24 KB, W^T per matrix
    __shared__ float    sB[64];
    int t = threadIdx.x;
    int base = blockIdx.x * 64;

    // ---- stage X tile (fp16, swizzled) ----
    {
        int r = t >> 2, q = t & 3;
        int grow = base + r; if (grow >= n) grow = n - 1;
        int idx = node_index[grow];
        const float4* srcp = (const float4*)(emb + (size_t)idx * 64 + q * 16);
        float4 v0 = srcp[0], v1 = srcp[1], v2 = srcp[2], v3 = srcp[3];
        half8 h0, h1;
        h0[0]=(_Float16)v0.x; h0[1]=(_Float16)v0.y; h0[2]=(_Float16)v0.z; h0[3]=(_Float16)v0.w;
        h0[4]=(_Float16)v1.x; h0[5]=(_Float16)v1.y; h0[6]=(_Float16)v1.z; h0[7]=(_Float16)v1.w;
        h1[0]=(_Float16)v2.x; h1[1]=(_Float16)v2.y; h1[2]=(_Float16)v2.z; h1[3]=(_Float16)v2.w;
        h1[4]=(_Float16)v3.x; h1[5]=(_Float16)v3.y; h1[6]=(_Float16)v3.z; h1[7]=(_Float16)v3.w;
        int g0 = q * 2;
        *(half8*)&sX[r * 64 + (((g0    ) ^ (r & 7)) << 3)] = h0;
        *(half8*)&sX[r * 64 + (((g0 + 1) ^ (r & 7)) << 3)] = h1;
    }
    // ---- stage W1, Wf, W2 transposed (fp16, swizzled) ----
    {
        int kk = t >> 4;          // 0..15
        int c0 = (t & 15) * 4;    // 0..60
        #pragma unroll
        for (int m = 0; m < 3; ++m) {
            const float* W = (m == 0) ? W1 : (m == 1) ? Wf : W2;
            #pragma unroll
            for (int p = 0; p < 4; ++p) {
                int k = p * 16 + kk;
                float4 w = *(const float4*)(W + k * 64 + c0);
                sWt[m * 4096 + (c0 + 0) * 64 + swz(c0 + 0, k)] = (_Float16)w.x;
                sWt[m * 4096 + (c0 + 1) * 64 + swz(c0 + 1, k)] = (_Float16)w.y;
                sWt[m * 4096 + (c0 + 2) * 64 + swz(c0 + 2, k)] = (_Float16)w.z;
                sWt[m * 4096 + (c0 + 3) * 64 + swz(c0 + 3, k)] = (_Float16)w.w;
            }
        }
    }
    if (t < 64) sB[t] = bfv[t];
    __syncthreads();

    int w    = t >> 6;
    int lane = t & 63;
    int l15  = lane & 15;
    int kg   = lane >> 4;          // 0..3
    int row  = w * 16 + l15;       // A-operand row within block
    int rsw  = row & 7;

    // ---- GEMM1 + GEMMf (share A) ----
    half8 a0 = *(const half8*)&sX[row * 64 + (((kg    ) ^ rsw) << 3)];
    half8 a1 = *(const half8*)&sX[row * 64 + (((4 + kg) ^ rsw) << 3)];
    f32x4 acc1[4], accf[4];
    #pragma unroll
    for (int ct = 0; ct < 4; ++ct) {
        int col = ct * 16 + l15;
        int csw = col & 7;
        half8 b10 = *(const half8*)&sWt[         col * 64 + (((kg    ) ^ csw) << 3)];
        half8 b11 = *(const half8*)&sWt[         col * 64 + (((4 + kg) ^ csw) << 3)];
        half8 bf0 = *(const half8*)&sWt[4096   + col * 64 + (((kg    ) ^ csw) << 3)];
        half8 bf1 = *(const half8*)&sWt[4096   + col * 64 + (((4 + kg) ^ csw) << 3)];
        f32x4 z = {0.f, 0.f, 0.f, 0.f};
        f32x4 u = __builtin_amdgcn_mfma_f32_16x16x32_f16(a0, b10, z, 0, 0, 0);
        acc1[ct] = __builtin_amdgcn_mfma_f32_16x16x32_f16(a1, b11, u, 0, 0, 0);
        f32x4 v = __builtin_amdgcn_mfma_f32_16x16x32_f16(a0, bf0, z, 0, 0, 0);
        accf[ct] = __builtin_amdgcn_mfma_f32_16x16x32_f16(a1, bf1, v, 0, 0, 0);
    }
    // ---- write xf (LDS, wave's own rows); keep acc1 in registers ----
    #pragma unroll
    for (int ct = 0; ct < 4; ++ct) {
        int col = ct * 16 + l15;
        #pragma unroll
        for (int r = 0; r < 4; ++r) {
            int rloc = w * 16 + kg * 4 + r;
            float xfv = elu_f(accf[ct][r] + sB[col]);
            sX[rloc * 64 + swz(rloc, col)] = (_Float16)xfv;
        }
    }
    __syncthreads();
    // ---- GEMM2: xw2 = xf @ W2 ; write packed, PRE-SCALED by dinv[row] ----
    half8 a20 = *(const half8*)&sX[row * 64 + (((kg    ) ^ rsw) << 3)];
    half8 a21 = *(const half8*)&sX[row * 64 + (((4 + kg) ^ rsw) << 3)];
    #pragma unroll
    for (int ct = 0; ct < 4; ++ct) {
        int col = ct * 16 + l15;
        int csw = col & 7;
        half8 b20 = *(const half8*)&sWt[8192 + col * 64 + (((kg    ) ^ csw) << 3)];
        half8 b21 = *(const half8*)&sWt[8192 + col * 64 + (((4 + kg) ^ csw) << 3)];
        f32x4 z = {0.f, 0.f, 0.f, 0.f};
        f32x4 u2 = __builtin_amdgcn_mfma_f32_16x16x32_f16(a20, b20, z, 0, 0, 0);
        f32x4 acc2 = __builtin_amdgcn_mfma_f32_16x16x32_f16(a21, b21, u2, 0, 0, 0);
        #pragma unroll
        for (int r = 0; r < 4; ++r) {
            int grow = base + w * 16 + kg * 4 + r;
            if (grow < n) {
                float dv = dinv[grow];
                xw12[(size_t)grow * 64 + col] = pack2h(acc1[ct][r] * dv, acc2[r] * dv);
            }
        }
    }
}

// ---------- K-gather (fused both convs + classifier + log_softmax) ----------
// one wave per dst node; meta = u32 (s:17 | ewq:15); y arrays pre-scaled by dinv[src].
__global__ __launch_bounds__(256) void k_gather(
    const unsigned* __restrict__ meta,
    const int*  __restrict__ rowptr,
    const float* __restrict__ dinv,
    const unsigned* __restrict__ xw12,
    const float* __restrict__ b1,
    const float* __restrict__ b2,
    const float* __restrict__ Wl,
    const float* __restrict__ bl,
    float* __restrict__ outp,
    int n)
{
    __shared__ float sWlT[16 * 68];   // Wl^T, padded row stride 68 floats
    __shared__ float sxv[4 * 64];     // per-wave xv staging
    int t = threadIdx.x;
    for (int i = t; i < 1024; i += 256) {
        int k = i & 63, c = i >> 6;
        sWlT[c * 68 + k] = Wl[k * 16 + c];
    }
    __syncthreads();

    int lane = t & 63;
    int wid  = t >> 6;
    int d = __builtin_amdgcn_readfirstlane(blockIdx.x * 4 + wid);
    if (d >= n) return;
    float di = dinv[d];
    float2 sf = unpack2h(xw12[(size_t)d * 64 + lane]);   // self-loop term (y[d])
    float acc1 = sf.x;
    float acc2 = sf.y;
    int e = rowptr[d], e1 = rowptr[d + 1];
    #pragma unroll 1
    for (; e + 8 <= e1; e += 8) {
        unsigned mm[8];
        #pragma unroll
        for (int j = 0; j < 8; ++j) mm[j] = meta[e + j];
        unsigned u[8];
        #pragma unroll
        for (int j = 0; j < 8; ++j)
            u[j] = xw12[(size_t)(mm[j] >> 15) * 64 + lane];
        #pragma unroll
        for (int j = 0; j < 8; ++j) {
            float ewv = (float)(mm[j] & 32767u) * (1.0f / 32768.0f);
            float2 f = unpack2h(u[j]);
            acc1 = fmaf(f.x, ewv, acc1);
            acc2 = fmaf(f.y, ewv, acc2);
        }
    }
    if (e + 4 <= e1) {
        unsigned mm[4];
        #pragma unroll
        for (int j = 0; j < 4; ++j) mm[j] = meta[e + j];
        unsigned u[4];
        #pragma unroll
        for (int j = 0; j < 4; ++j)
            u[j] = xw12[(size_t)(mm[j] >> 15) * 64 + lane];
        #pragma unroll
        for (int j = 0; j < 4; ++j) {
            float ewv = (float)(mm[j] & 32767u) * (1.0f / 32768.0f);
            float2 f = unpack2h(u[j]);
            acc1 = fmaf(f.x, ewv, acc1);
            acc2 = fmaf(f.y, ewv, acc2);
        }
        e += 4;
    }
    #pragma unroll 1
    for (; e < e1; ++e) {
        unsigned m = meta[e];
        float ewv = (float)(m & 32767u) * (1.0f / 32768.0f);
        float2 f = unpack2h(xw12[(size_t)(m >> 15) * 64 + lane]);
        acc1 = fmaf(f.x, ewv, acc1);
        acc2 = fmaf(f.y, ewv, acc2);
    }
    acc1 *= di;                 // deferred dinv[d] factor
    acc2 *= di;
    float r1 = elu_f(acc1 + b1[lane]);
    float xv = r1 + elu_f(acc2 + b2[lane]);

    // ---- classifier: lane (g = lane>>4, c = lane&15) computes one class partial ----
    sxv[wid * 64 + lane] = xv;                 // same-wave LDS rw, no barrier
    int g = lane >> 4, c = lane & 15;
    const float* xvp = &sxv[wid * 64 + g * 16];
    const float* wp  = &sWlT[c * 68 + g * 16];
    float partial = 0.f;
    #pragma unroll
    for (int p4 = 0; p4 < 4; ++p4) {
        float4 x4 = *(const float4*)(xvp + p4 * 4);
        float4 w4 = *(const float4*)(wp  + p4 * 4);
        partial = fmaf(x4.x, w4.x, partial);
        partial = fmaf(x4.y, w4.y, partial);
        partial = fmaf(x4.z, w4.z, partial);
        partial = fmaf(x4.w, w4.w, partial);
    }
    partial += __shfl_xor(partial, 16, 64);
    partial += __shfl_xor(partial, 32, 64);
    float logit = partial + bl[c];
    float m = logit;
    #pragma unroll
    for (int off = 1; off < 16; off <<= 1)
        m = fmaxf(m, __shfl_xor(m, off, 64));
    float ex = __expf(logit - m);
    float es = ex;
    #pragma unroll
    for (int off = 1; off < 16; off <<= 1)
        es += __shfl_xor(es, off, 64);
    float lse = m + __logf(es);
    if (lane < 16)
        outp[(size_t)d * 16 + lane] = logit - lse;   // coalesced 64B row
}

// ---------- launch ----------
extern "C" void kernel_launch(void* const* d_in, const int* in_sizes, int n_in,
                              void* d_out, int out_size, void* d_ws, size_t ws_size,
                              hipStream_t stream)
{
    const int*   node_index = (const int*)d_in[0];
    const int*   edge_index = (const int*)d_in[1];
    const float* ew  = (const float*)d_in[2];
    const float* emb = (const float*)d_in[3];
    const float* W1  = (const float*)d_in[4];
    const float* b1  = (const float*)d_in[5];
    const float* W2  = (const float*)d_in[6];
    const float* b2  = (const float*)d_in[7];
    const float* Wf  = (const float*)d_in[8];
    const float* bfv = (const float*)d_in[9];
    const float* Wl  = (const float*)d_in[10];
    const float* bl  = (const float*)d_in[11];

    const int N = in_sizes[0];
    const int E = in_sizes[2];
    const int* srcp = edge_index;
    const int* dstp = edge_index + E;
    const int nbuckets = (N + 255) >> 8;    // 391

    char* ws = (char*)d_ws;
    size_t off = 0;
    auto alloc = [&](size_t bytes) {
        void* p = ws + off;
        off += (bytes + 255) & ~size_t(255);
        return p;
    };
    unsigned* gcur    = (unsigned*)alloc((size_t)nbuckets * 4);
    unsigned* bbase   = (unsigned*)alloc((size_t)(nbuckets + 1) * 4);
    uint2*    scratch = (uint2*)   alloc((size_t)nbuckets * BSTRIDE * 8);
    int*      rowptr  = (int*)     alloc((size_t)(N + 1) * 4);
    float*    dinv    = (float*)   alloc((size_t)N * 4);
    unsigned* meta    = (unsigned*)alloc((size_t)E * 4);
    unsigned* xw12    = (unsigned*)alloc((size_t)N * 64 * 4);

    int nb_edges  = (E + 255) / 256;
    int nb_front  = (N + 63) / 64;
    int nb_gather = (N + 3) / 4;

    hipMemsetAsync(gcur, 0, (size_t)nbuckets * 4, stream);
    k_part<<<nb_edges, 256, 0, stream>>>(srcp, dstp, ew, gcur, scratch, E);
    k_bscan<<<1, 512, 0, stream>>>(gcur, bbase, nbuckets, rowptr, N, E);
    k_bucket<<<nbuckets, 256, 0, stream>>>(scratch, gcur, bbase, rowptr, dinv, meta, N);
    k_front<<<nb_front, 256, 0, stream>>>(node_index, emb, W1, Wf, bfv, W2, dinv, xw12, N);
    k_gather<<<nb_gather, 256, 0, stream>>>(meta, rowptr, dinv, xw12,
                                            b1, b2, Wl, bl, (float*)d_out, N);
}

// Round 14
// 322.101 us; speedup vs baseline: 2.4726x; 2.4726x over previous
//
#include <hip/hip_runtime.h>
#include <hip/hip_fp16.h>
#include <math.h>

#define PACK     67108864.0              // 2^26
#define PACK_INV 1.4901161193847656e-08  // 2^-26

typedef _Float16 half8 __attribute__((ext_vector_type(8)));
typedef float    f32x4 __attribute__((ext_vector_type(4)));

// ---------- helpers ----------
__device__ __forceinline__ float elu_f(float v) {
    return v > 0.f ? v : expm1f(v);
}
__device__ __forceinline__ unsigned pack2h(float a, float b) {
    __half2 h = __floats2half2_rn(a, b);
    return *(unsigned*)&h;
}
__device__ __forceinline__ float2 unpack2h(unsigned u) {
    __half2 h = *(__half2*)&u;
    return __half22float2(h);
}
// granule swizzle within a 64-fp16 row: spreads the 16B granules across banks
__device__ __forceinline__ int swz(int line, int e) {
    return ((((e >> 3) ^ (line & 7)) << 3) | (e & 7));
}

// ---------- FAT kernel: front (MFMA) blocks + hist (atomic) blocks, concurrent ----------
// blocks [0, nfront): xw12 = packed fp16 (X@W1, elu(X@Wf+bf)@W2) for 64 rows
// blocks [nfront, nfront+nhist): packed[dst] += ew + 2^26 ; rank[e] = old count
__global__ __launch_bounds__(256) void k_fronthist(
    const int* __restrict__ node_index,
    const float* __restrict__ emb,
    const float* __restrict__ W1,
    const float* __restrict__ Wf,
    const float* __restrict__ bfv,
    const float* __restrict__ W2,
    unsigned* __restrict__ xw12,
    int n, int nfront,
    const int* __restrict__ dst,
    const float* __restrict__ ew,
    double* __restrict__ packed,
    int* __restrict__ rank, int E)
{
    __shared__ _Float16 sX[64 * 64];       // 8 KB
    __shared__ _Float16 sWt[3 * 64 * 64];  // 24 KB
    __shared__ float    sB[64];
    int t = threadIdx.x;

    if (blockIdx.x >= nfront) {
        // ---------------- hist body (no LDS use) ----------------
        int i = (blockIdx.x - nfront) * 256 + t;
        if (i < E) {
            double old = unsafeAtomicAdd(&packed[dst[i]], (double)ew[i] + PACK);
            rank[i] = (int)(old * PACK_INV);   // floor: frac part < 2^-20
        }
        return;
    }

    // ---------------- front body ----------------
    int base = blockIdx.x * 64;
    // ---- stage X tile (fp16, swizzled) ----
    {
        int r = t >> 2, q = t & 3;
        int grow = base + r; if (grow >= n) grow = n - 1;
        int idx = node_index[grow];
        const float4* srcp = (const float4*)(emb + (size_t)idx * 64 + q * 16);
        float4 v0 = srcp[0], v1 = srcp[1], v2 = srcp[2], v3 = srcp[3];
        half8 h0, h1;
        h0[0]=(_Float16)v0.x; h0[1]=(_Float16)v0.y; h0[2]=(_Float16)v0.z; h0[3]=(_Float16)v0.w;
        h0[4]=(_Float16)v1.x; h0[5]=(_Float16)v1.y; h0[6]=(_Float16)v1.z; h0[7]=(_Float16)v1.w;
        h1[0]=(_Float16)v2.x; h1[1]=(_Float16)v2.y; h1[2]=(_Float16)v2.z; h1[3]=(_Float16)v2.w;
        h1[4]=(_Float16)v3.x; h1[5]=(_Float16)v3.y; h1[6]=(_Float16)v3.z; h1[7]=(_Float16)v3.w;
        int g0 = q * 2;
        *(half8*)&sX[r * 64 + (((g0    ) ^ (r & 7)) << 3)] = h0;
        *(half8*)&sX[r * 64 + (((g0 + 1) ^ (r & 7)) << 3)] = h1;
    }
    // ---- stage W1, Wf, W2 transposed (fp16, swizzled) ----
    {
        int kk = t >> 4;          // 0..15
        int c0 = (t & 15) * 4;    // 0..60
        #pragma unroll
        for (int m = 0; m < 3; ++m) {
            const float* W = (m == 0) ? W1 : (m == 1) ? Wf : W2;
            #pragma unroll
            for (int p = 0; p < 4; ++p) {
                int k = p * 16 + kk;
                float4 w = *(const float4*)(W + k * 64 + c0);
                sWt[m * 4096 + (c0 + 0) * 64 + swz(c0 + 0, k)] = (_Float16)w.x;
                sWt[m * 4096 + (c0 + 1) * 64 + swz(c0 + 1, k)] = (_Float16)w.y;
                sWt[m * 4096 + (c0 + 2) * 64 + swz(c0 + 2, k)] = (_Float16)w.z;
                sWt[m * 4096 + (c0 + 3) * 64 + swz(c0 + 3, k)] = (_Float16)w.w;
            }
        }
    }
    if (t < 64) sB[t] = bfv[t];
    __syncthreads();

    int w    = t >> 6;
    int lane = t & 63;
    int l15  = lane & 15;
    int kg   = lane >> 4;          // 0..3
    int row  = w * 16 + l15;       // A-operand row within block
    int rsw  = row & 7;

    // ---- GEMM1 + GEMMf (share A) ----
    half8 a0 = *(const half8*)&sX[row * 64 + (((kg    ) ^ rsw) << 3)];
    half8 a1 = *(const half8*)&sX[row * 64 + (((4 + kg) ^ rsw) << 3)];
    f32x4 acc1[4], accf[4];
    #pragma unroll
    for (int ct = 0; ct < 4; ++ct) {
        int col = ct * 16 + l15;
        int csw = col & 7;
        half8 b10 = *(const half8*)&sWt[         col * 64 + (((kg    ) ^ csw) << 3)];
        half8 b11 = *(const half8*)&sWt[         col * 64 + (((4 + kg) ^ csw) << 3)];
        half8 bf0 = *(const half8*)&sWt[4096   + col * 64 + (((kg    ) ^ csw) << 3)];
        half8 bf1 = *(const half8*)&sWt[4096   + col * 64 + (((4 + kg) ^ csw) << 3)];
        f32x4 z = {0.f, 0.f, 0.f, 0.f};
        f32x4 u = __builtin_amdgcn_mfma_f32_16x16x32_f16(a0, b10, z, 0, 0, 0);
        acc1[ct] = __builtin_amdgcn_mfma_f32_16x16x32_f16(a1, b11, u, 0, 0, 0);
        f32x4 v = __builtin_amdgcn_mfma_f32_16x16x32_f16(a0, bf0, z, 0, 0, 0);
        accf[ct] = __builtin_amdgcn_mfma_f32_16x16x32_f16(a1, bf1, v, 0, 0, 0);
    }
    // ---- write xf (LDS, wave's own rows); keep acc1 in registers ----
    #pragma unroll
    for (int ct = 0; ct < 4; ++ct) {
        int col = ct * 16 + l15;
        #pragma unroll
        for (int r = 0; r < 4; ++r) {
            int rloc = w * 16 + kg * 4 + r;
            float xfv = elu_f(accf[ct][r] + sB[col]);
            sX[rloc * 64 + swz(rloc, col)] = (_Float16)xfv;
        }
    }
    __syncthreads();
    // ---- GEMM2: xw2 = xf @ W2 ; write packed (xw1, xw2) ----
    half8 a20 = *(const half8*)&sX[row * 64 + (((kg    ) ^ rsw) << 3)];
    half8 a21 = *(const half8*)&sX[row * 64 + (((4 + kg) ^ rsw) << 3)];
    #pragma unroll
    for (int ct = 0; ct < 4; ++ct) {
        int col = ct * 16 + l15;
        int csw = col & 7;
        half8 b20 = *(const half8*)&sWt[8192 + col * 64 + (((kg    ) ^ csw) << 3)];
        half8 b21 = *(const half8*)&sWt[8192 + col * 64 + (((4 + kg) ^ csw) << 3)];
        f32x4 z = {0.f, 0.f, 0.f, 0.f};
        f32x4 u2 = __builtin_amdgcn_mfma_f32_16x16x32_f16(a20, b20, z, 0, 0, 0);
        f32x4 acc2 = __builtin_amdgcn_mfma_f32_16x16x32_f16(a21, b21, u2, 0, 0, 0);
        #pragma unroll
        for (int r = 0; r < 4; ++r) {
            int grow = base + w * 16 + kg * 4 + r;
            if (grow < n)
                xw12[(size_t)grow * 64 + col] = pack2h(acc1[ct][r], acc2[r]);
        }
    }
}

// ---------- K2: decode packed -> dinv + cnt ; per-block sums of cnt ----------
__global__ __launch_bounds__(256) void k_decode_blocksum(
    const double* __restrict__ packed,
    float* __restrict__ dinv,
    int* __restrict__ cnt,
    int* __restrict__ bsum, int n)
{
    __shared__ int sm[256];
    int t = threadIdx.x;
    int i = blockIdx.x * 256 + t;
    int v = 0;
    if (i < n) {
        double val = packed[i];
        double c = floor(val * PACK_INV);
        v = (int)c;
        float deg = (float)(val - c * PACK);
        dinv[i] = rsqrtf(deg + 1.0f);
        cnt[i] = v;
    }
    sm[t] = v;
    __syncthreads();
    for (int off = 128; off > 0; off >>= 1) {
        if (t < off) sm[t] += sm[t + off];
        __syncthreads();
    }
    if (t == 0) bsum[blockIdx.x] = sm[0];
}

// ---------- scan step 2: exclusive scan of block sums (single block, nb<=512) ----------
__global__ __launch_bounds__(512) void k_scan_bsum(int* __restrict__ bsum, int nb) {
    __shared__ int sm[512];
    int t = threadIdx.x;
    int v = (t < nb) ? bsum[t] : 0;
    sm[t] = v;
    __syncthreads();
    for (int off = 1; off < 512; off <<= 1) {
        int x = sm[t];
        int y = (t >= off) ? sm[t - off] : 0;
        __syncthreads();
        sm[t] = x + y;
        __syncthreads();
    }
    if (t < nb) bsum[t] = sm[t] - v;   // exclusive
}

// ---------- scan step 3: rowptr = blockoff + intra-block exclusive scan ----------
__global__ __launch_bounds__(256) void k_scan_apply(const int* __restrict__ cnt,
                                                    const int* __restrict__ bsum,
                                                    int* __restrict__ rowptr, int n) {
    __shared__ int sm[256];
    int t = threadIdx.x;
    int i = blockIdx.x * 256 + t;
    int v = (i < n) ? cnt[i] : 0;
    sm[t] = v;
    __syncthreads();
    for (int off = 1; off < 256; off <<= 1) {
        int x = sm[t];
        int y = (t >= off) ? sm[t - off] : 0;
        __syncthreads();
        sm[t] = x + y;
        __syncthreads();
    }
    int excl = sm[t] - v + bsum[blockIdx.x];
    if (i < n) {
        rowptr[i] = excl;
        if (i == n - 1) rowptr[n] = excl + v;
    }
}

// ---------- K-fill (atomic-free): meta[rowptr[dst]+rank] = (src, norm) ----------
__global__ __launch_bounds__(256) void k_fill(const int* __restrict__ src,
                                              const int* __restrict__ dst,
                                              const float* __restrict__ ew,
                                              const int* __restrict__ rank,
                                              const float* __restrict__ dinv,
                                              const int* __restrict__ rowptr,
                                              int2* __restrict__ meta, int E) {
    int i = blockIdx.x * 256 + threadIdx.x;
    if (i >= E) return;
    int s = src[i], d = dst[i];
    float nrm = dinv[s] * ew[i] * dinv[d];
    int pos = rowptr[d] + rank[i];
    meta[pos] = make_int2(s, __float_as_int(nrm));
}

// ---------- K-gather (fused both convs + classifier + log_softmax) ----------
// one wave per dst node, lane = feature dim; ONE packed uint load per edge.
// Classifier: LDS-staged Wl^T + per-lane single-class partial dot (cheap epilogue).
__global__ __launch_bounds__(256) void k_gather(
    const int2* __restrict__ meta,
    const int*  __restrict__ rowptr,
    const float* __restrict__ dinv,
    const unsigned* __restrict__ xw12,
    const float* __restrict__ b1,
    const float* __restrict__ b2,
    const float* __restrict__ Wl,
    const float* __restrict__ bl,
    float* __restrict__ outp,
    int n)
{
    __shared__ float sWlT[16 * 68];   // Wl^T, padded row stride 68 floats
    __shared__ float sxv[4 * 64];     // per-wave xv staging
    int t = threadIdx.x;
    // stage Wl^T once per block: sWlT[c][k] = Wl[k][c]
    for (int i = t; i < 1024; i += 256) {
        int k = i & 63, c = i >> 6;            // c in 0..15 over 4 iterations
        sWlT[c * 68 + k] = Wl[k * 16 + c];
    }
    __syncthreads();

    int lane = t & 63;
    int wid  = t >> 6;
    int d = __builtin_amdgcn_readfirstlane(blockIdx.x * 4 + wid);
    if (d >= n) return;
    float di = dinv[d];
    float di2 = di * di;
    float2 sf = unpack2h(xw12[(size_t)d * 64 + lane]);   // self-loop
    float acc1 = sf.x * di2;
    float acc2 = sf.y * di2;
    int e = rowptr[d], e1 = rowptr[d + 1];
    #pragma unroll 1
    for (; e + 8 <= e1; e += 8) {
        int2 m[8];
        #pragma unroll
        for (int j = 0; j < 8; ++j) m[j] = meta[e + j];
        unsigned u[8];
        #pragma unroll
        for (int j = 0; j < 8; ++j)
            u[j] = xw12[(size_t)m[j].x * 64 + lane];
        #pragma unroll
        for (int j = 0; j < 8; ++j) {
            float nrm = __int_as_float(m[j].y);
            float2 f = unpack2h(u[j]);
            acc1 = fmaf(f.x, nrm, acc1);
            acc2 = fmaf(f.y, nrm, acc2);
        }
    }
    if (e + 4 <= e1) {
        int2 m[4];
        #pragma unroll
        for (int j = 0; j < 4; ++j) m[j] = meta[e + j];
        unsigned u[4];
        #pragma unroll
        for (int j = 0; j < 4; ++j)
            u[j] = xw12[(size_t)m[j].x * 64 + lane];
        #pragma unroll
        for (int j = 0; j < 4; ++j) {
            float nrm = __int_as_float(m[j].y);
            float2 f = unpack2h(u[j]);
            acc1 = fmaf(f.x, nrm, acc1);
            acc2 = fmaf(f.y, nrm, acc2);
        }
        e += 4;
    }
    #pragma unroll 1
    for (; e < e1; ++e) {
        int2 m = meta[e];
        float nrm = __int_as_float(m.y);
        float2 f = unpack2h(xw12[(size_t)m.x * 64 + lane]);
        acc1 = fmaf(f.x, nrm, acc1);
        acc2 = fmaf(f.y, nrm, acc2);
    }
    float r1 = elu_f(acc1 + b1[lane]);
    float xv = r1 + elu_f(acc2 + b2[lane]);

    // ---- classifier: lane (g = lane>>4, c = lane&15) computes one class
    //      partial over its 16-element slice; 2 shfl to merge groups ----
    sxv[wid * 64 + lane] = xv;                 // same-wave LDS rw, no barrier
    int g = lane >> 4, c = lane & 15;
    const float* xvp = &sxv[wid * 64 + g * 16];
    const float* wp  = &sWlT[c * 68 + g * 16];
    float partial = 0.f;
    #pragma unroll
    for (int p4 = 0; p4 < 4; ++p4) {
        float4 x4 = *(const float4*)(xvp + p4 * 4);   // broadcast within group
        float4 w4 = *(const float4*)(wp  + p4 * 4);
        partial = fmaf(x4.x, w4.x, partial);
        partial = fmaf(x4.y, w4.y, partial);
        partial = fmaf(x4.z, w4.z, partial);
        partial = fmaf(x4.w, w4.w, partial);
    }
    partial += __shfl_xor(partial, 16, 64);
    partial += __shfl_xor(partial, 32, 64);
    float logit = partial + bl[c];
    // softmax over the 16 classes spread across each 16-lane group
    float m = logit;
    #pragma unroll
    for (int off = 1; off < 16; off <<= 1)
        m = fmaxf(m, __shfl_xor(m, off, 64));
    float ex = __expf(logit - m);
    float es = ex;
    #pragma unroll
    for (int off = 1; off < 16; off <<= 1)
        es += __shfl_xor(es, off, 64);
    float lse = m + __logf(es);
    if (lane < 16)
        outp[(size_t)d * 16 + lane] = logit - lse;   // coalesced 64B row
}

// ---------- launch ----------
extern "C" void kernel_launch(void* const* d_in, const int* in_sizes, int n_in,
                              void* d_out, int out_size, void* d_ws, size_t ws_size,
                              hipStream_t stream)
{
    const int*   node_index = (const int*)d_in[0];
    const int*   edge_index = (const int*)d_in[1];
    const float* ew  = (const float*)d_in[2];
    const float* emb = (const float*)d_in[3];
    const float* W1  = (const float*)d_in[4];
    const float* b1  = (const float*)d_in[5];
    const float* W2  = (const float*)d_in[6];
    const float* b2  = (const float*)d_in[7];
    const float* Wf  = (const float*)d_in[8];
    const float* bfv = (const float*)d_in[9];
    const float* Wl  = (const float*)d_in[10];
    const float* bl  = (const float*)d_in[11];

    const int N = in_sizes[0];
    const int E = in_sizes[2];
    const int* srcp = edge_index;
    const int* dstp = edge_index + E;

    char* ws = (char*)d_ws;
    size_t off = 0;
    auto alloc = [&](size_t bytes) {
        void* p = ws + off;
        off += (bytes + 255) & ~size_t(255);
        return p;
    };
    double*   packed = (double*)  alloc((size_t)N * 8);
    int*      rank   = (int*)     alloc((size_t)E * 4);
    int*      cnt    = (int*)     alloc((size_t)N * 4);
    int*      bsum   = (int*)     alloc(512 * 4);
    int*      rowptr = (int*)     alloc((size_t)(N + 1) * 4);
    float*    dinv   = (float*)   alloc((size_t)N * 4);
    int2*     meta   = (int2*)    alloc((size_t)E * 8);
    unsigned* xw12   = (unsigned*)alloc((size_t)N * 64 * 4);

    int nb_nodes  = (N + 255) / 256;                        // 391 (<=512 for scan)
    int nb_edges  = (E + 255) / 256;
    int nb_front  = (N + 63) / 64;                          // 64 rows per block
    int nb_gather = (N + 3) / 4;                            // 4 waves (nodes) per block

    hipMemsetAsync(packed, 0, (size_t)N * 8, stream);
    k_fronthist<<<nb_front + nb_edges, 256, 0, stream>>>(
        node_index, emb, W1, Wf, bfv, W2, xw12, N, nb_front,
        dstp, ew, packed, rank, E);
    k_decode_blocksum<<<nb_nodes, 256, 0, stream>>>(packed, dinv, cnt, bsum, N);
    k_scan_bsum<<<1, 512, 0, stream>>>(bsum, nb_nodes);
    k_scan_apply<<<nb_nodes, 256, 0, stream>>>(cnt, bsum, rowptr, N);
    k_fill<<<nb_edges, 256, 0, stream>>>(srcp, dstp, ew, rank, dinv, rowptr, meta, E);
    k_gather<<<nb_gather, 256, 0, stream>>>(meta, rowptr, dinv, xw12,
                                            b1, b2, Wl, bl, (float*)d_out, N);
}